// Round 3
// baseline (989.440 us; speedup 1.0000x reference)
//
#include <hip/hip_runtime.h>
#include <hip/hip_bf16.h>
#include <hip/hip_fp16.h>

#define NN 100000
#define NE 3200000
#define IN_F 128
#define HID 32

#define NB 782          // buckets: bucket = dst >> 7, 128 nodes each
#define NBP1 (NB + 1)
#define BNODES 128
#define PBLK 782        // partition blocks
#define EPB 4096        // edges per partition block (512 thr x 8)
#define SSPAN 4608      // per-bucket record span bound (mean 4092 + 8 sigma); = 9*512

typedef __hip_bfloat16 bf16;
typedef __attribute__((ext_vector_type(8))) short s16x8;   // 8 bf16 (4 VGPRs)
typedef __attribute__((ext_vector_type(4))) float f32x4;   // MFMA C/D

// ---------------- partition: LDS counting sort, ALL global writes dense ----------------
// Also accumulates wsum[dst] (degree weight sums) via NATIVE global f32 atomics
// (unsafeAtomicAdd -> global_atomic_add_f32, no CAS loop); wsum zeroed by memset.
// Self-loop (+1) folded in at k_hs.
__global__ __launch_bounds__(512) void k_part(const int* __restrict__ ei,
                                              const float* __restrict__ ew,
                                              int* __restrict__ offs,
                                              uint2* __restrict__ raw,
                                              float* __restrict__ wsum) {
    __shared__ int hist[NB];
    __shared__ int start[NB];
    __shared__ int wtot8[8];
    __shared__ uint2 sp[EPB];             // 32 KB

    int t = threadIdx.x;
    int blk = blockIdx.x;
    for (int b = t; b < NB; b += 512) hist[b] = 0;
    __syncthreads();

    unsigned pk[8]; unsigned wb[8]; int bkt[8];
    int base_e = blk * EPB;
#pragma unroll
    for (int j = 0; j < 8; j++) {
        int e = base_e + j * 512 + t;
        if (e < NE) {
            int src = __builtin_nontemporal_load(ei + e);
            int dst = __builtin_nontemporal_load(ei + NE + e);
            float w = __builtin_nontemporal_load(ew + e);
            bkt[j] = dst >> 7;
            pk[j] = (unsigned)src | ((unsigned)(dst & 127) << 20);
            wb[j] = __float_as_uint(w);
        } else bkt[j] = -1;
    }
#pragma unroll
    for (int j = 0; j < 8; j++)
        if (bkt[j] >= 0) {
            atomicAdd(&hist[bkt[j]], 1);
            int dst = (bkt[j] << 7) | (int)((pk[j] >> 20) & 127);
            unsafeAtomicAdd(&wsum[dst], __uint_as_float(wb[j]));   // native f32 atomic
        }
    __syncthreads();

    // exclusive scan over 782 bins (512 threads x 2, shuffle-based)
    int e0 = 2 * t, e1 = 2 * t + 1;
    int h0 = (e0 < NB) ? hist[e0] : 0;
    int h1 = (e1 < NB) ? hist[e1] : 0;
    int psum = h0 + h1;
    int lane = t & 63;
    int incl = psum;
#pragma unroll
    for (int off = 1; off < 64; off <<= 1) {
        int up = __shfl_up(incl, off, 64);
        if (lane >= off) incl += up;
    }
    int wid = t >> 6;
    if (lane == 63) wtot8[wid] = incl;
    __syncthreads();
    int woff = 0;
    for (int wj = 0; wj < wid; wj++) woff += wtot8[wj];
    int exc = woff + incl - psum;
    if (e0 < NB) start[e0] = exc;
    if (e1 < NB) start[e1] = exc + h0;
    __syncthreads();

    int total = start[NB - 1] + hist[NB - 1];
    int* orow = offs + (size_t)blk * NBP1;
    for (int b = t; b < NB; b += 512) orow[b] = start[b];
    if (t == 0) orow[NB] = total;
    __syncthreads();   // orow reads of start[] complete before cursor mutation

    // LDS counting scatter (start[] becomes cursor)
#pragma unroll
    for (int j = 0; j < 8; j++) {
        if (bkt[j] >= 0) {
            int pos = atomicAdd(&start[bkt[j]], 1);
            sp[pos] = make_uint2(pk[j], wb[j]);
        }
    }
    __syncthreads();

    // dense, coalesced copy to block-private region (written exactly once)
    uint2* r = raw + (size_t)blk * EPB;
    for (int i = t; i < total; i += 512) r[i] = sp[i];
}

// ---------------- offs transpose ([blk][bucket] -> [bucket][blk]) ----------------
__global__ __launch_bounds__(256) void k_trans(const int* __restrict__ in, int* __restrict__ out) {
    __shared__ int tile[32][33];
    int c0 = blockIdx.x * 32, r0 = blockIdx.y * 32;
    int tx = threadIdx.x & 31, ty = threadIdx.x >> 5;   // 32 x 8
    for (int i = ty; i < 32; i += 8) {
        int r = r0 + i, c = c0 + tx;
        if (r < PBLK && c < NBP1) tile[i][tx] = in[(size_t)r * NBP1 + c];
    }
    __syncthreads();
    for (int i = ty; i < 32; i += 8) {
        int c = c0 + i, r = r0 + tx;
        if (c < NBP1 && r < PBLK) out[(size_t)c * PBLK + r] = tile[tx][i];
    }
}

// ---------------- W1 -> bf16 MFMA B-fragments, lane-packed ----------------
__global__ void k_w1frag(const float* __restrict__ W1, unsigned short* __restrict__ wfrag) {
    int lane = threadIdx.x;   // 64 threads
    int q = lane >> 4;
    int n0 = lane & 15;
#pragma unroll
    for (int ks = 0; ks < 4; ks++) {
#pragma unroll
        for (int nt = 0; nt < 2; nt++) {
            int fi = ks * 2 + nt;
            int n = n0 + 16 * nt;
#pragma unroll
            for (int j = 0; j < 8; j++) {
                int k = ks * 32 + q * 8 + j;
                float v = W1[k * HID + n];
                __hip_bfloat16 bv = __float2bfloat16(v);
                wfrag[((size_t)fi * 64 + lane) * 8 + j] = *(unsigned short*)&bv;
            }
        }
    }
}

// ---------------- hs = dinv * (x @ W1) via MFMA, stored bf16; also writes dinv ----------------
__global__ __launch_bounds__(256) void k_hs(const float* __restrict__ x,
                                            const unsigned short* __restrict__ wfrag,
                                            const float* __restrict__ wsum,
                                            float* __restrict__ dinv,
                                            bf16* __restrict__ hs) {
    int t = threadIdx.x;
    int lane = t & 63;
    int wv = t >> 6;
    int base = blockIdx.x * 64 + wv * 16;
    int m = lane & 15;
    int q = lane >> 4;
    int node = base + m;

    s16x8 wf[8];
    const s16x8* wp = (const s16x8*)wfrag;
#pragma unroll
    for (int fi = 0; fi < 8; fi++) wf[fi] = wp[fi * 64 + lane];

    f32x4 acc0 = {0.f, 0.f, 0.f, 0.f};
    f32x4 acc1 = {0.f, 0.f, 0.f, 0.f};

    const float* rowp = x + (size_t)node * IN_F + q * 8;
    bool valid = (node < NN);

#pragma unroll
    for (int ks = 0; ks < 4; ks++) {
        float4 f0 = {0,0,0,0}, f1 = {0,0,0,0};
        if (valid) {
            const float4* xr = (const float4*)(rowp + ks * 32);
            f0 = xr[0]; f1 = xr[1];
        }
        union { s16x8 v; unsigned u32[4]; } af;
        __hip_bfloat162 p0 = __float22bfloat162_rn({f0.x, f0.y});
        __hip_bfloat162 p1 = __float22bfloat162_rn({f0.z, f0.w});
        __hip_bfloat162 p2 = __float22bfloat162_rn({f1.x, f1.y});
        __hip_bfloat162 p3 = __float22bfloat162_rn({f1.z, f1.w});
        af.u32[0] = *(unsigned*)&p0;
        af.u32[1] = *(unsigned*)&p1;
        af.u32[2] = *(unsigned*)&p2;
        af.u32[3] = *(unsigned*)&p3;
        acc0 = __builtin_amdgcn_mfma_f32_16x16x32_bf16(af.v, wf[ks * 2 + 0], acc0, 0, 0, 0);
        acc1 = __builtin_amdgcn_mfma_f32_16x16x32_bf16(af.v, wf[ks * 2 + 1], acc1, 0, 0, 0);
    }

    int f = lane & 15;
#pragma unroll
    for (int r = 0; r < 4; r++) {
        int n2 = base + q * 4 + r;
        if (n2 < NN) {
            float dv = rsqrtf(wsum[n2] + 1.0f);   // +1 = self-loop weight
            if (f == 0) dinv[n2] = dv;
            hs[(size_t)n2 * HID + f]      = __float2bfloat16(dv * acc0[r]);
            hs[(size_t)n2 * HID + f + 16] = __float2bfloat16(dv * acc1[r]);
        }
    }
}

// ---------------- fused per-bucket gather + LDS-atomic aggregation + epilogue ----------------
// One block per bucket (128 dst nodes). Reads this bucket's records directly from the
// partition-block-private raw regions (runid map), accumulates messages into a padded
// LDS accumulator with NATIVE ds_add_f32 atomics (unsafeAtomicAdd — order-free), then
// applies self-loop + dinv + bias + relu + W2 dot per node. No within-bucket sort.
__global__ __launch_bounds__(512) void k_agg(const int* __restrict__ offsT,
                                             const uint2* __restrict__ raw,
                                             const bf16* __restrict__ hs,
                                             const float* __restrict__ dinv,
                                             const float* __restrict__ b1, const float* __restrict__ W2,
                                             const float* __restrict__ b2, float* __restrict__ out) {
    __shared__ unsigned short runid[SSPAN];   //  9.2 KB
    __shared__ int P[PBLK + 1];               //  3.1 KB
    __shared__ int O0[PBLK];                  //  3.1 KB
    __shared__ float acc[BNODES][33];         // 16.9 KB, padded: bank = (dl + f) & 31
    __shared__ int wt8[8];

    int t = threadIdx.x;
    int b = blockIdx.x;

    // zero accumulator
    for (int i = t; i < BNODES * 33; i += 512) ((float*)acc)[i] = 0.f;

    // run lengths for this bucket across 782 partition blocks (2 per thread)
    int e0 = 2 * t, e1 = 2 * t + 1;
    int l0 = 0, l1 = 0, o0v = 0, o1v = 0;
    if (e0 < PBLK) {
        o0v = offsT[(size_t)b * PBLK + e0];
        l0  = offsT[(size_t)(b + 1) * PBLK + e0] - o0v;
    }
    if (e1 < PBLK) {
        o1v = offsT[(size_t)b * PBLK + e1];
        l1  = offsT[(size_t)(b + 1) * PBLK + e1] - o1v;
    }
    int psum = l0 + l1;
    int lane = t & 63;
    int incl = psum;
#pragma unroll
    for (int off = 1; off < 64; off <<= 1) {
        int up = __shfl_up(incl, off, 64);
        if (lane >= off) incl += up;
    }
    int wid = t >> 6;
    if (lane == 63) wt8[wid] = incl;
    __syncthreads();          // covers wt8 + acc zeroing
    int woff = 0;
    for (int wj = 0; wj < wid; wj++) woff += wt8[wj];
    int exc = woff + incl - psum;
    if (e0 < PBLK) { P[e0] = exc;      O0[e0] = o0v; }
    if (e1 < PBLK) { P[e1] = exc + l0; O0[e1] = o1v; }
    if (t == 0) {
        int s = 0;
#pragma unroll
        for (int j = 0; j < 8; j++) s += wt8[j];
        P[PBLK] = s;
    }
    __syncthreads();

    int total = min(P[PBLK], SSPAN);

    // build d -> run map (short serial LDS fills, ~5 per run)
    for (int r = t; r < PBLK; r += 512) {
        int p0 = P[r], p1 = min(P[r + 1], SSPAN);
        for (int i = p0; i < p1; i++) runid[i] = (unsigned short)r;
    }
    __syncthreads();

    int l = t & 15;
    const __hip_bfloat162* hs2 = (const __hip_bfloat162*)hs;  // row stride 16

    // main edge loop: 16-lane groups, 16 records per round via broadcast.
    // Tail lanes hold (src=0, w=0) so the 16-wide unroll is uniform (zero-adds harmless).
    for (int k = 0; k < 9; k++) {
        int gbase = (t & ~15) + k * 512;
        if (gbase >= total) break;              // group-uniform condition
        int d = gbase + l;
        unsigned sreg = 0; float wreg = 0.f;
        if (d < total) {
            int r = runid[d];
            uint2 rec = raw[(size_t)r * EPB + O0[r] + (d - P[r])];
            sreg = rec.x; wreg = __uint_as_float(rec.y);
        }
#pragma unroll
        for (int jb = 0; jb < 16; jb += 8) {
            unsigned s0 = __shfl(sreg, jb + 0, 16), s1 = __shfl(sreg, jb + 1, 16);
            unsigned s2 = __shfl(sreg, jb + 2, 16), s3 = __shfl(sreg, jb + 3, 16);
            unsigned s4 = __shfl(sreg, jb + 4, 16), s5 = __shfl(sreg, jb + 5, 16);
            unsigned s6 = __shfl(sreg, jb + 6, 16), s7 = __shfl(sreg, jb + 7, 16);
            float w0 = __shfl(wreg, jb + 0, 16), w1 = __shfl(wreg, jb + 1, 16);
            float w2 = __shfl(wreg, jb + 2, 16), w3 = __shfl(wreg, jb + 3, 16);
            float w4 = __shfl(wreg, jb + 4, 16), w5 = __shfl(wreg, jb + 5, 16);
            float w6 = __shfl(wreg, jb + 6, 16), w7 = __shfl(wreg, jb + 7, 16);
            __hip_bfloat162 h0 = hs2[(size_t)(s0 & 0xFFFFF) * 16 + l];
            __hip_bfloat162 h1 = hs2[(size_t)(s1 & 0xFFFFF) * 16 + l];
            __hip_bfloat162 h2 = hs2[(size_t)(s2 & 0xFFFFF) * 16 + l];
            __hip_bfloat162 h3 = hs2[(size_t)(s3 & 0xFFFFF) * 16 + l];
            __hip_bfloat162 h4 = hs2[(size_t)(s4 & 0xFFFFF) * 16 + l];
            __hip_bfloat162 h5 = hs2[(size_t)(s5 & 0xFFFFF) * 16 + l];
            __hip_bfloat162 h6 = hs2[(size_t)(s6 & 0xFFFFF) * 16 + l];
            __hip_bfloat162 h7 = hs2[(size_t)(s7 & 0xFFFFF) * 16 + l];
            float2 f0 = __bfloat1622float2(h0);
            unsafeAtomicAdd(&acc[(s0 >> 20) & 127][2 * l],     w0 * f0.x);
            unsafeAtomicAdd(&acc[(s0 >> 20) & 127][2 * l + 1], w0 * f0.y);
            float2 f1 = __bfloat1622float2(h1);
            unsafeAtomicAdd(&acc[(s1 >> 20) & 127][2 * l],     w1 * f1.x);
            unsafeAtomicAdd(&acc[(s1 >> 20) & 127][2 * l + 1], w1 * f1.y);
            float2 f2 = __bfloat1622float2(h2);
            unsafeAtomicAdd(&acc[(s2 >> 20) & 127][2 * l],     w2 * f2.x);
            unsafeAtomicAdd(&acc[(s2 >> 20) & 127][2 * l + 1], w2 * f2.y);
            float2 f3 = __bfloat1622float2(h3);
            unsafeAtomicAdd(&acc[(s3 >> 20) & 127][2 * l],     w3 * f3.x);
            unsafeAtomicAdd(&acc[(s3 >> 20) & 127][2 * l + 1], w3 * f3.y);
            float2 f4 = __bfloat1622float2(h4);
            unsafeAtomicAdd(&acc[(s4 >> 20) & 127][2 * l],     w4 * f4.x);
            unsafeAtomicAdd(&acc[(s4 >> 20) & 127][2 * l + 1], w4 * f4.y);
            float2 f5 = __bfloat1622float2(h5);
            unsafeAtomicAdd(&acc[(s5 >> 20) & 127][2 * l],     w5 * f5.x);
            unsafeAtomicAdd(&acc[(s5 >> 20) & 127][2 * l + 1], w5 * f5.y);
            float2 f6 = __bfloat1622float2(h6);
            unsafeAtomicAdd(&acc[(s6 >> 20) & 127][2 * l],     w6 * f6.x);
            unsafeAtomicAdd(&acc[(s6 >> 20) & 127][2 * l + 1], w6 * f6.y);
            float2 f7 = __bfloat1622float2(h7);
            unsafeAtomicAdd(&acc[(s7 >> 20) & 127][2 * l],     w7 * f7.x);
            unsafeAtomicAdd(&acc[(s7 >> 20) & 127][2 * l + 1], w7 * f7.y);
        }
    }
    __syncthreads();

    // epilogue: 4 threads per node, 8 features each; self-loop + dinv + b1 + relu + W2
    int nl = t >> 2;            // 0..127
    int fo = (t & 3) * 8;
    int node = b * BNODES + nl;
    if (node < NN) {
        float dv = dinv[node];
        const __hip_bfloat162* selfp = hs2 + (size_t)node * 16 + (t & 3) * 4;
        float psum = 0.f;
#pragma unroll
        for (int jj = 0; jj < 4; jj++) {
            float2 fsv = __bfloat1622float2(selfp[jj]);
            int f = fo + 2 * jj;
            float v0 = dv * (acc[nl][f]     + fsv.x) + b1[f];
            float v1 = dv * (acc[nl][f + 1] + fsv.y) + b1[f + 1];
            v0 = fmaxf(v0, 0.f);
            v1 = fmaxf(v1, 0.f);
            psum += v0 * W2[f] + v1 * W2[f + 1];
        }
        psum += __shfl_xor(psum, 1, 4);
        psum += __shfl_xor(psum, 2, 4);
        if ((t & 3) == 0) out[node] = psum + b2[0];
    }
}

// ---------------- launch ----------------
extern "C" void kernel_launch(void* const* d_in, const int* in_sizes, int n_in,
                              void* d_out, int out_size, void* d_ws, size_t ws_size,
                              hipStream_t stream) {
    const float* x  = (const float*)d_in[0];
    const int*   ei = (const int*)d_in[1];
    const float* ew = (const float*)d_in[2];
    const float* W1 = (const float*)d_in[3];
    const float* b1 = (const float*)d_in[4];
    const float* W2 = (const float*)d_in[5];
    const float* b2 = (const float*)d_in[6];
    float* out = (float*)d_out;

    char* ws = (char*)d_ws;
    // ws layout (bytes), total ~37.7 MB. raw stays live through k_agg (no overlap).
    uint2*          raw      = (uint2*)         (ws + 0);           // PBLK*EPB uint2 = 25,624,576
    int*            offs     = (int*)           (ws + 25624576);    // PBLK*NBP1 int = 2,449,224 -> pad 28,073,984
    int*            offsT    = (int*)           (ws + 28073984);    // NBP1*PBLK int -> pad 30,523,392
    bf16*           hs       = (bf16*)          (ws + 30523392);    // NN*HID bf16 = 6,400,000 -> 36,923,392
    float*          wsum     = (float*)         (ws + 36923392);    // NN floats -> 37,323,392
    float*          dinv     = (float*)         (ws + 37323392);    // NN floats -> 37,723,392
    unsigned short* wfrag    = (unsigned short*)(ws + 37723392);    // 8 KB -> 37,731,584

    (void)hipMemsetAsync(wsum, 0, NN * sizeof(float), stream);
    k_w1frag<<<1, 64, 0, stream>>>(W1, wfrag);
    k_part<<<PBLK, 512, 0, stream>>>(ei, ew, offs, raw, wsum);
    k_trans<<<dim3((NBP1 + 31) / 32, (PBLK + 31) / 32), 256, 0, stream>>>(offs, offsT);
    k_hs<<<(NN + 63) / 64, 256, 0, stream>>>(x, wfrag, wsum, dinv, hs);
    k_agg<<<NB, 512, 0, stream>>>(offsT, raw, hs, dinv, b1, W2, b2, out);
}

// Round 4
// 322.247 us; speedup vs baseline: 3.0704x; 3.0704x over previous
//
#include <hip/hip_runtime.h>
#include <hip/hip_bf16.h>
#include <hip/hip_fp16.h>

#define NN 100000
#define NE 3200000
#define IN_F 128
#define HID 32

#define NB 782          // buckets: bucket = dst >> 7, 128 nodes each
#define NBP1 (NB + 1)
#define BNODES 128
#define PBLK 782        // partition blocks
#define EPB 4096        // edges per partition block (512 thr x 8)
#define SSPAN 4608      // per-bucket record span bound (mean 4092 + 8 sigma); = 9*512
#define WSCALE 16777216.0f          // 2^24 fixed-point for weighted degree
#define WSCALE_INV 5.9604644775390625e-08f

typedef __hip_bfloat16 bf16;
typedef __attribute__((ext_vector_type(8))) short s16x8;   // 8 bf16 (4 VGPRs)
typedef __attribute__((ext_vector_type(4))) float f32x4;   // MFMA C/D

// ---------------- partition: LDS counting sort, ALL global writes dense ----------------
// Weighted degree accumulated via NATIVE global INT atomics (fixed-point 2^24);
// wsumi zeroed by hipMemsetAsync. Self-loop (+1) folded in at k_hs.
__global__ __launch_bounds__(512) void k_part(const int* __restrict__ ei,
                                              const float* __restrict__ ew,
                                              int* __restrict__ offs,
                                              uint2* __restrict__ raw,
                                              int* __restrict__ wsumi) {
    __shared__ int hist[NB];
    __shared__ int start[NB];
    __shared__ int wtot8[8];
    __shared__ uint2 sp[EPB];             // 32 KB

    int t = threadIdx.x;
    int blk = blockIdx.x;
    for (int b = t; b < NB; b += 512) hist[b] = 0;
    __syncthreads();

    unsigned pk[8]; unsigned wb[8]; int bkt[8];
    int base_e = blk * EPB;
#pragma unroll
    for (int j = 0; j < 8; j++) {
        int e = base_e + j * 512 + t;
        if (e < NE) {
            int src = __builtin_nontemporal_load(ei + e);
            int dst = __builtin_nontemporal_load(ei + NE + e);
            float w = __builtin_nontemporal_load(ew + e);
            bkt[j] = dst >> 7;
            pk[j] = (unsigned)src | ((unsigned)(dst & 127) << 20);
            wb[j] = __float_as_uint(w);
        } else bkt[j] = -1;
    }
#pragma unroll
    for (int j = 0; j < 8; j++)
        if (bkt[j] >= 0) {
            atomicAdd(&hist[bkt[j]], 1);
            int dst = (bkt[j] << 7) | (int)((pk[j] >> 20) & 127);
            atomicAdd(&wsumi[dst], (int)(__uint_as_float(wb[j]) * WSCALE));  // native int atomic
        }
    __syncthreads();

    // exclusive scan over 782 bins (512 threads x 2, shuffle-based)
    int e0 = 2 * t, e1 = 2 * t + 1;
    int h0 = (e0 < NB) ? hist[e0] : 0;
    int h1 = (e1 < NB) ? hist[e1] : 0;
    int psum = h0 + h1;
    int lane = t & 63;
    int incl = psum;
#pragma unroll
    for (int off = 1; off < 64; off <<= 1) {
        int up = __shfl_up(incl, off, 64);
        if (lane >= off) incl += up;
    }
    int wid = t >> 6;
    if (lane == 63) wtot8[wid] = incl;
    __syncthreads();
    int woff = 0;
    for (int wj = 0; wj < wid; wj++) woff += wtot8[wj];
    int exc = woff + incl - psum;
    if (e0 < NB) start[e0] = exc;
    if (e1 < NB) start[e1] = exc + h0;
    __syncthreads();

    int total = start[NB - 1] + hist[NB - 1];
    int* orow = offs + (size_t)blk * NBP1;
    for (int b = t; b < NB; b += 512) orow[b] = start[b];
    if (t == 0) orow[NB] = total;
    __syncthreads();   // orow reads of start[] complete before cursor mutation

    // LDS counting scatter (start[] becomes cursor)
#pragma unroll
    for (int j = 0; j < 8; j++) {
        if (bkt[j] >= 0) {
            int pos = atomicAdd(&start[bkt[j]], 1);
            sp[pos] = make_uint2(pk[j], wb[j]);
        }
    }
    __syncthreads();

    // dense, coalesced copy to block-private region (written exactly once)
    uint2* r = raw + (size_t)blk * EPB;
    for (int i = t; i < total; i += 512) r[i] = sp[i];
}

// ---------------- offs transpose ([blk][bucket] -> [bucket][blk]) ----------------
__global__ __launch_bounds__(256) void k_trans(const int* __restrict__ in, int* __restrict__ out) {
    __shared__ int tile[32][33];
    int c0 = blockIdx.x * 32, r0 = blockIdx.y * 32;
    int tx = threadIdx.x & 31, ty = threadIdx.x >> 5;   // 32 x 8
    for (int i = ty; i < 32; i += 8) {
        int r = r0 + i, c = c0 + tx;
        if (r < PBLK && c < NBP1) tile[i][tx] = in[(size_t)r * NBP1 + c];
    }
    __syncthreads();
    for (int i = ty; i < 32; i += 8) {
        int c = c0 + i, r = r0 + tx;
        if (c < NBP1 && r < PBLK) out[(size_t)c * PBLK + r] = tile[tx][i];
    }
}

// ---------------- W1 -> bf16 MFMA B-fragments, lane-packed ----------------
__global__ void k_w1frag(const float* __restrict__ W1, unsigned short* __restrict__ wfrag) {
    int lane = threadIdx.x;   // 64 threads
    int q = lane >> 4;
    int n0 = lane & 15;
#pragma unroll
    for (int ks = 0; ks < 4; ks++) {
#pragma unroll
        for (int nt = 0; nt < 2; nt++) {
            int fi = ks * 2 + nt;
            int n = n0 + 16 * nt;
#pragma unroll
            for (int j = 0; j < 8; j++) {
                int k = ks * 32 + q * 8 + j;
                float v = W1[k * HID + n];
                __hip_bfloat16 bv = __float2bfloat16(v);
                wfrag[((size_t)fi * 64 + lane) * 8 + j] = *(unsigned short*)&bv;
            }
        }
    }
}

// ---------------- hs = dinv * (x @ W1) via MFMA, stored bf16; also writes dinv ----------------
__global__ __launch_bounds__(256) void k_hs(const float* __restrict__ x,
                                            const unsigned short* __restrict__ wfrag,
                                            const int* __restrict__ wsumi,
                                            float* __restrict__ dinv,
                                            bf16* __restrict__ hs) {
    int t = threadIdx.x;
    int lane = t & 63;
    int wv = t >> 6;
    int base = blockIdx.x * 64 + wv * 16;
    int m = lane & 15;
    int q = lane >> 4;
    int node = base + m;

    s16x8 wf[8];
    const s16x8* wp = (const s16x8*)wfrag;
#pragma unroll
    for (int fi = 0; fi < 8; fi++) wf[fi] = wp[fi * 64 + lane];

    f32x4 acc0 = {0.f, 0.f, 0.f, 0.f};
    f32x4 acc1 = {0.f, 0.f, 0.f, 0.f};

    const float* rowp = x + (size_t)node * IN_F + q * 8;
    bool valid = (node < NN);

#pragma unroll
    for (int ks = 0; ks < 4; ks++) {
        float4 f0 = {0,0,0,0}, f1 = {0,0,0,0};
        if (valid) {
            const float4* xr = (const float4*)(rowp + ks * 32);
            f0 = xr[0]; f1 = xr[1];
        }
        union { s16x8 v; unsigned u32[4]; } af;
        __hip_bfloat162 p0 = __float22bfloat162_rn({f0.x, f0.y});
        __hip_bfloat162 p1 = __float22bfloat162_rn({f0.z, f0.w});
        __hip_bfloat162 p2 = __float22bfloat162_rn({f1.x, f1.y});
        __hip_bfloat162 p3 = __float22bfloat162_rn({f1.z, f1.w});
        af.u32[0] = *(unsigned*)&p0;
        af.u32[1] = *(unsigned*)&p1;
        af.u32[2] = *(unsigned*)&p2;
        af.u32[3] = *(unsigned*)&p3;
        acc0 = __builtin_amdgcn_mfma_f32_16x16x32_bf16(af.v, wf[ks * 2 + 0], acc0, 0, 0, 0);
        acc1 = __builtin_amdgcn_mfma_f32_16x16x32_bf16(af.v, wf[ks * 2 + 1], acc1, 0, 0, 0);
    }

    int f = lane & 15;
#pragma unroll
    for (int r = 0; r < 4; r++) {
        int n2 = base + q * 4 + r;
        if (n2 < NN) {
            float dv = rsqrtf((float)wsumi[n2] * WSCALE_INV + 1.0f);   // +1 = self-loop
            if (f == 0) dinv[n2] = dv;
            hs[(size_t)n2 * HID + f]      = __float2bfloat16(dv * acc0[r]);
            hs[(size_t)n2 * HID + f + 16] = __float2bfloat16(dv * acc1[r]);
        }
    }
}

// ---------------- fused: per-bucket gather + LDS counting sort + register pull + epilogue ----
// Phase A == proven k_sort (register gather, LDS int-hist, scan, LDS scatter) but scatter
// target is LDS se[] (no global srt round-trip). Phase B == proven pull k_agg, records
// broadcast-read from LDS (same-address ds_read_b64, no bpermute), accumulate in regs.
__global__ __launch_bounds__(512) void k_agg(const int* __restrict__ offsT,
                                             const uint2* __restrict__ raw,
                                             const bf16* __restrict__ hs,
                                             const float* __restrict__ dinv,
                                             const float* __restrict__ b1, const float* __restrict__ W2,
                                             const float* __restrict__ b2, float* __restrict__ out) {
    __shared__ uint2 se[SSPAN];               // 36.9 KB (sorted records); aliased by runid in phase A
    __shared__ int P[PBLK + 1];               //  3.1 KB
    __shared__ int basearr[PBLK];             //  3.1 KB  (= O0[r] - P[r])
    __shared__ int hist[BNODES];
    __shared__ int scanbuf[BNODES];
    __shared__ int cur[BNODES];
    __shared__ int wt8[8];

    unsigned short* runid = (unsigned short*)se;   // dead before se is written

    int t = threadIdx.x;
    int b = blockIdx.x;
    if (t < BNODES) hist[t] = 0;

    // run lengths for this bucket across 782 partition blocks (2 per thread)
    int e0 = 2 * t, e1 = 2 * t + 1;
    int l0 = 0, l1 = 0, o0v = 0, o1v = 0;
    if (e0 < PBLK) {
        o0v = offsT[(size_t)b * PBLK + e0];
        l0  = offsT[(size_t)(b + 1) * PBLK + e0] - o0v;
    }
    if (e1 < PBLK) {
        o1v = offsT[(size_t)b * PBLK + e1];
        l1  = offsT[(size_t)(b + 1) * PBLK + e1] - o1v;
    }
    int psum = l0 + l1;
    int lane = t & 63;
    int incl = psum;
#pragma unroll
    for (int off = 1; off < 64; off <<= 1) {
        int up = __shfl_up(incl, off, 64);
        if (lane >= off) incl += up;
    }
    int wid = t >> 6;
    if (lane == 63) wt8[wid] = incl;
    __syncthreads();
    int woff = 0;
    for (int wj = 0; wj < wid; wj++) woff += wt8[wj];
    int exc = woff + incl - psum;
    if (e0 < PBLK) { P[e0] = exc;      basearr[e0] = o0v - exc; }
    if (e1 < PBLK) { P[e1] = exc + l0; basearr[e1] = o1v - (exc + l0); }
    if (t == 0) {
        int s = 0;
#pragma unroll
        for (int j = 0; j < 8; j++) s += wt8[j];
        P[PBLK] = s;
    }
    __syncthreads();

    int total = min(P[PBLK], SSPAN);

    // build d -> run map in the se region (short serial LDS fills, ~5 per run)
    for (int r = t; r < PBLK; r += 512) {
        int p0 = P[r], p1 = min(P[r + 1], SSPAN);
        for (int i = p0; i < p1; i++) runid[i] = (unsigned short)r;
    }
    __syncthreads();

    // pass 1: coalesced gather into REGISTERS + node histogram (<=9 recs/thread)
    uint2 rr[9];
#pragma unroll
    for (int k = 0; k < 9; k++) {
        int d = t + k * 512;
        if (d < total) {
            int r = runid[d];
            uint2 rec = raw[(size_t)r * EPB + (basearr[r] + d)];
            rr[k] = rec;
            int dl = (rec.x >> 20) & 127;
            atomicAdd(&hist[dl], 1);
        }
    }
    __syncthreads();   // runid dead from here; se region reusable

    // inclusive scan of node hist (Hillis-Steele over 128)
    if (t < BNODES) scanbuf[t] = hist[t];
    __syncthreads();
    for (int off = 1; off < BNODES; off <<= 1) {
        int v = 0;
        if (t < BNODES && t >= off) v = scanbuf[t - off];
        __syncthreads();
        if (t < BNODES) scanbuf[t] += v;
        __syncthreads();
    }
    if (t < BNODES) cur[t] = scanbuf[t] - hist[t];   // exclusive start
    __syncthreads();

    // pass 2: scatter from registers into se at final sorted positions (src pre-masked)
#pragma unroll
    for (int k = 0; k < 9; k++) {
        int d = t + k * 512;
        if (d < total) {
            uint2 rec = rr[k];
            int dl = (rec.x >> 20) & 127;
            int pos = atomicAdd(&cur[dl], 1);   // LDS int atomic
            se[pos] = make_uint2(rec.x & 0xFFFFF, rec.y);
        }
    }
    __syncthreads();

    // ---- phase B: per-group pull, register accumulate, fused epilogue ----
    int gid = t >> 4;          // 0..31, 16 lanes each
    int l = t & 15;
    const __hip_bfloat162* hs2 = (const __hip_bfloat162*)hs;  // row stride 16
#pragma unroll
    for (int nn = 0; nn < 4; nn++) {
        int dl = gid * 4 + nn;
        int cnt = hist[dl];
        int rs = scanbuf[dl] - cnt;
        float a0 = 0.f, a1 = 0.f;
        for (int bse = 0; bse < cnt; bse += 8) {
            int rem = cnt - bse;
            uint2 q0 = se[rs + bse];
            uint2 q1 = se[rs + bse + (rem > 1 ? 1 : 0)];
            uint2 q2 = se[rs + bse + (rem > 2 ? 2 : 0)];
            uint2 q3 = se[rs + bse + (rem > 3 ? 3 : 0)];
            uint2 q4 = se[rs + bse + (rem > 4 ? 4 : 0)];
            uint2 q5 = se[rs + bse + (rem > 5 ? 5 : 0)];
            uint2 q6 = se[rs + bse + (rem > 6 ? 6 : 0)];
            uint2 q7 = se[rs + bse + (rem > 7 ? 7 : 0)];
            float w0 = __uint_as_float(q0.y);
            float w1 = rem > 1 ? __uint_as_float(q1.y) : 0.f;
            float w2 = rem > 2 ? __uint_as_float(q2.y) : 0.f;
            float w3 = rem > 3 ? __uint_as_float(q3.y) : 0.f;
            float w4 = rem > 4 ? __uint_as_float(q4.y) : 0.f;
            float w5 = rem > 5 ? __uint_as_float(q5.y) : 0.f;
            float w6 = rem > 6 ? __uint_as_float(q6.y) : 0.f;
            float w7 = rem > 7 ? __uint_as_float(q7.y) : 0.f;
            __hip_bfloat162 h0 = hs2[(size_t)q0.x * 16 + l];
            __hip_bfloat162 h1 = hs2[(size_t)q1.x * 16 + l];
            __hip_bfloat162 h2 = hs2[(size_t)q2.x * 16 + l];
            __hip_bfloat162 h3 = hs2[(size_t)q3.x * 16 + l];
            __hip_bfloat162 h4 = hs2[(size_t)q4.x * 16 + l];
            __hip_bfloat162 h5 = hs2[(size_t)q5.x * 16 + l];
            __hip_bfloat162 h6 = hs2[(size_t)q6.x * 16 + l];
            __hip_bfloat162 h7 = hs2[(size_t)q7.x * 16 + l];
            float2 f0 = __bfloat1622float2(h0); a0 += w0 * f0.x; a1 += w0 * f0.y;
            float2 f1 = __bfloat1622float2(h1); a0 += w1 * f1.x; a1 += w1 * f1.y;
            float2 f2 = __bfloat1622float2(h2); a0 += w2 * f2.x; a1 += w2 * f2.y;
            float2 f3 = __bfloat1622float2(h3); a0 += w3 * f3.x; a1 += w3 * f3.y;
            float2 f4 = __bfloat1622float2(h4); a0 += w4 * f4.x; a1 += w4 * f4.y;
            float2 f5 = __bfloat1622float2(h5); a0 += w5 * f5.x; a1 += w5 * f5.y;
            float2 f6 = __bfloat1622float2(h6); a0 += w6 * f6.x; a1 += w6 * f6.y;
            float2 f7 = __bfloat1622float2(h7); a0 += w7 * f7.x; a1 += w7 * f7.y;
        }
        int node = b * BNODES + dl;
        if (node < NN) {
            float dv = dinv[node];
            float2 fs = __bfloat1622float2(hs2[(size_t)node * 16 + l]);
            float v0 = dv * (a0 + fs.x) + b1[2 * l];
            float v1 = dv * (a1 + fs.y) + b1[2 * l + 1];
            v0 = fmaxf(v0, 0.f);
            v1 = fmaxf(v1, 0.f);
            float ps = v0 * W2[2 * l] + v1 * W2[2 * l + 1];
#pragma unroll
            for (int m2 = 8; m2 >= 1; m2 >>= 1) ps += __shfl_xor(ps, m2, 16);
            if (l == 0) out[node] = ps + b2[0];
        }
    }
}

// ---------------- launch ----------------
extern "C" void kernel_launch(void* const* d_in, const int* in_sizes, int n_in,
                              void* d_out, int out_size, void* d_ws, size_t ws_size,
                              hipStream_t stream) {
    const float* x  = (const float*)d_in[0];
    const int*   ei = (const int*)d_in[1];
    const float* ew = (const float*)d_in[2];
    const float* W1 = (const float*)d_in[3];
    const float* b1 = (const float*)d_in[4];
    const float* W2 = (const float*)d_in[5];
    const float* b2 = (const float*)d_in[6];
    float* out = (float*)d_out;

    char* ws = (char*)d_ws;
    // ws layout (bytes), total ~37.7 MB. raw stays live through k_agg (no overlap).
    uint2*          raw      = (uint2*)         (ws + 0);           // PBLK*EPB uint2 = 25,624,576
    int*            offs     = (int*)           (ws + 25624576);    // PBLK*NBP1 int = 2,449,224 -> pad 28,073,984
    int*            offsT    = (int*)           (ws + 28073984);    // NBP1*PBLK int -> pad 30,523,392
    bf16*           hs       = (bf16*)          (ws + 30523392);    // NN*HID bf16 = 6,400,000 -> 36,923,392
    int*            wsumi    = (int*)           (ws + 36923392);    // NN ints -> 37,323,392
    float*          dinv     = (float*)         (ws + 37323392);    // NN floats -> 37,723,392
    unsigned short* wfrag    = (unsigned short*)(ws + 37723392);    // 8 KB -> 37,731,584

    (void)hipMemsetAsync(wsumi, 0, NN * sizeof(int), stream);
    k_w1frag<<<1, 64, 0, stream>>>(W1, wfrag);
    k_part<<<PBLK, 512, 0, stream>>>(ei, ew, offs, raw, wsumi);
    k_trans<<<dim3((NBP1 + 31) / 32, (PBLK + 31) / 32), 256, 0, stream>>>(offs, offsT);
    k_hs<<<(NN + 63) / 64, 256, 0, stream>>>(x, wfrag, wsumi, dinv, hs);
    k_agg<<<NB, 512, 0, stream>>>(offsT, raw, hs, dinv, b1, W2, b2, out);
}

// Round 5
// 217.915 us; speedup vs baseline: 4.5405x; 1.4788x over previous
//
#include <hip/hip_runtime.h>
#include <hip/hip_bf16.h>
#include <hip/hip_fp16.h>

#define NN 100000
#define NE 3200000
#define IN_F 128
#define HID 32

#define NB 782          // buckets: bucket = dst >> 7, 128 nodes each
#define NBP1 (NB + 1)
#define BNODES 128
#define PBLK 782        // partition blocks
#define EPB 4096        // edges per partition block (512 thr x 8)
#define SSPAN 4608      // per-bucket record span bound (mean 4092 + 8 sigma); = 9*512

typedef __hip_bfloat16 bf16;
typedef __attribute__((ext_vector_type(8))) short s16x8;   // 8 bf16 (4 VGPRs)
typedef __attribute__((ext_vector_type(4))) float f32x4;   // MFMA C/D

// ---------------- partition: LDS counting sort, ALL global writes dense ----------------
// NO global atomics (the round-4 145us regression was 3.2M scattered device-scope
// atomics). Weighted degree is now computed per-bucket in k_deg via LDS atomics.
__global__ __launch_bounds__(512) void k_part(const int* __restrict__ ei,
                                              const float* __restrict__ ew,
                                              int* __restrict__ offs,
                                              uint2* __restrict__ raw) {
    __shared__ int hist[NB];
    __shared__ int start[NB];
    __shared__ int wtot8[8];
    __shared__ uint2 sp[EPB];             // 32 KB

    int t = threadIdx.x;
    int blk = blockIdx.x;
    for (int b = t; b < NB; b += 512) hist[b] = 0;
    __syncthreads();

    unsigned pk[8]; unsigned wb[8]; int bkt[8];
    int base_e = blk * EPB;
#pragma unroll
    for (int j = 0; j < 8; j++) {
        int e = base_e + j * 512 + t;
        if (e < NE) {
            int src = __builtin_nontemporal_load(ei + e);
            int dst = __builtin_nontemporal_load(ei + NE + e);
            float w = __builtin_nontemporal_load(ew + e);
            bkt[j] = dst >> 7;
            pk[j] = (unsigned)src | ((unsigned)(dst & 127) << 20);
            wb[j] = __float_as_uint(w);
        } else bkt[j] = -1;
    }
#pragma unroll
    for (int j = 0; j < 8; j++)
        if (bkt[j] >= 0) atomicAdd(&hist[bkt[j]], 1);
    __syncthreads();

    // exclusive scan over 782 bins (512 threads x 2, shuffle-based)
    int e0 = 2 * t, e1 = 2 * t + 1;
    int h0 = (e0 < NB) ? hist[e0] : 0;
    int h1 = (e1 < NB) ? hist[e1] : 0;
    int psum = h0 + h1;
    int lane = t & 63;
    int incl = psum;
#pragma unroll
    for (int off = 1; off < 64; off <<= 1) {
        int up = __shfl_up(incl, off, 64);
        if (lane >= off) incl += up;
    }
    int wid = t >> 6;
    if (lane == 63) wtot8[wid] = incl;
    __syncthreads();
    int woff = 0;
    for (int wj = 0; wj < wid; wj++) woff += wtot8[wj];
    int exc = woff + incl - psum;
    if (e0 < NB) start[e0] = exc;
    if (e1 < NB) start[e1] = exc + h0;
    __syncthreads();

    int total = start[NB - 1] + hist[NB - 1];
    int* orow = offs + (size_t)blk * NBP1;
    for (int b = t; b < NB; b += 512) orow[b] = start[b];
    if (t == 0) orow[NB] = total;
    __syncthreads();   // orow reads of start[] complete before cursor mutation

    // LDS counting scatter (start[] becomes cursor)
#pragma unroll
    for (int j = 0; j < 8; j++) {
        if (bkt[j] >= 0) {
            int pos = atomicAdd(&start[bkt[j]], 1);
            sp[pos] = make_uint2(pk[j], wb[j]);
        }
    }
    __syncthreads();

    // dense, coalesced copy to block-private region (written exactly once)
    uint2* r = raw + (size_t)blk * EPB;
    for (int i = t; i < total; i += 512) r[i] = sp[i];
}

// ---------------- offs transpose ([blk][bucket] -> [bucket][blk]) ----------------
__global__ __launch_bounds__(256) void k_trans(const int* __restrict__ in, int* __restrict__ out) {
    __shared__ int tile[32][33];
    int c0 = blockIdx.x * 32, r0 = blockIdx.y * 32;
    int tx = threadIdx.x & 31, ty = threadIdx.x >> 5;   // 32 x 8
    for (int i = ty; i < 32; i += 8) {
        int r = r0 + i, c = c0 + tx;
        if (r < PBLK && c < NBP1) tile[i][tx] = in[(size_t)r * NBP1 + c];
    }
    __syncthreads();
    for (int i = ty; i < 32; i += 8) {
        int c = c0 + i, r = r0 + tx;
        if (c < NBP1 && r < PBLK) out[(size_t)c * PBLK + r] = tile[tx][i];
    }
}

// ---------------- per-bucket weighted degree -> dinv (LDS atomics, dense writes) ----------
// One block per bucket: run-length scan + runid map + coalesced gather of this bucket's
// records from raw; accumulate w into wsum[128] via LDS float atomics (3.2M total across
// grid — proven cheap in the original k_sort); write dinv densely. No global atomics.
__global__ __launch_bounds__(512) void k_deg(const int* __restrict__ offsT,
                                             const uint2* __restrict__ raw,
                                             float* __restrict__ dinv) {
    __shared__ unsigned short runid[SSPAN];   //  9.2 KB
    __shared__ int P[PBLK + 1];               //  3.1 KB
    __shared__ int basearr[PBLK];             //  3.1 KB  (= O0[r] - P[r])
    __shared__ float wsum[BNODES];
    __shared__ int wt8[8];

    int t = threadIdx.x;
    int b = blockIdx.x;
    if (t < BNODES) wsum[t] = 0.f;

    int e0 = 2 * t, e1 = 2 * t + 1;
    int l0 = 0, l1 = 0, o0v = 0, o1v = 0;
    if (e0 < PBLK) {
        o0v = offsT[(size_t)b * PBLK + e0];
        l0  = offsT[(size_t)(b + 1) * PBLK + e0] - o0v;
    }
    if (e1 < PBLK) {
        o1v = offsT[(size_t)b * PBLK + e1];
        l1  = offsT[(size_t)(b + 1) * PBLK + e1] - o1v;
    }
    int psum = l0 + l1;
    int lane = t & 63;
    int incl = psum;
#pragma unroll
    for (int off = 1; off < 64; off <<= 1) {
        int up = __shfl_up(incl, off, 64);
        if (lane >= off) incl += up;
    }
    int wid = t >> 6;
    if (lane == 63) wt8[wid] = incl;
    __syncthreads();          // covers wsum init
    int woff = 0;
    for (int wj = 0; wj < wid; wj++) woff += wt8[wj];
    int exc = woff + incl - psum;
    if (e0 < PBLK) { P[e0] = exc;      basearr[e0] = o0v - exc; }
    if (e1 < PBLK) { P[e1] = exc + l0; basearr[e1] = o1v - (exc + l0); }
    if (t == 0) {
        int s = 0;
#pragma unroll
        for (int j = 0; j < 8; j++) s += wt8[j];
        P[PBLK] = s;
    }
    __syncthreads();

    int total = min(P[PBLK], SSPAN);

    for (int r = t; r < PBLK; r += 512) {
        int p0 = P[r], p1 = min(P[r + 1], SSPAN);
        for (int i = p0; i < p1; i++) runid[i] = (unsigned short)r;
    }
    __syncthreads();

#pragma unroll
    for (int k = 0; k < 9; k++) {
        int d = t + k * 512;
        if (d < total) {
            int r = runid[d];
            uint2 rec = raw[(size_t)r * EPB + (basearr[r] + d)];
            atomicAdd(&wsum[(rec.x >> 20) & 127], __uint_as_float(rec.y));
        }
    }
    __syncthreads();

    if (t < BNODES) {
        int node = b * BNODES + t;
        if (node < NN) dinv[node] = rsqrtf(wsum[t] + 1.0f);   // +1 = self-loop
    }
}

// ---------------- W1 -> bf16 MFMA B-fragments, lane-packed ----------------
__global__ void k_w1frag(const float* __restrict__ W1, unsigned short* __restrict__ wfrag) {
    int lane = threadIdx.x;   // 64 threads
    int q = lane >> 4;
    int n0 = lane & 15;
#pragma unroll
    for (int ks = 0; ks < 4; ks++) {
#pragma unroll
        for (int nt = 0; nt < 2; nt++) {
            int fi = ks * 2 + nt;
            int n = n0 + 16 * nt;
#pragma unroll
            for (int j = 0; j < 8; j++) {
                int k = ks * 32 + q * 8 + j;
                float v = W1[k * HID + n];
                __hip_bfloat16 bv = __float2bfloat16(v);
                wfrag[((size_t)fi * 64 + lane) * 8 + j] = *(unsigned short*)&bv;
            }
        }
    }
}

// ---------------- hs = dinv * (x @ W1) via MFMA, stored bf16 ----------------
__global__ __launch_bounds__(256) void k_hs(const float* __restrict__ x,
                                            const unsigned short* __restrict__ wfrag,
                                            const float* __restrict__ dinv,
                                            bf16* __restrict__ hs) {
    int t = threadIdx.x;
    int lane = t & 63;
    int wv = t >> 6;
    int base = blockIdx.x * 64 + wv * 16;
    int m = lane & 15;
    int q = lane >> 4;
    int node = base + m;

    s16x8 wf[8];
    const s16x8* wp = (const s16x8*)wfrag;
#pragma unroll
    for (int fi = 0; fi < 8; fi++) wf[fi] = wp[fi * 64 + lane];

    f32x4 acc0 = {0.f, 0.f, 0.f, 0.f};
    f32x4 acc1 = {0.f, 0.f, 0.f, 0.f};

    const float* rowp = x + (size_t)node * IN_F + q * 8;
    bool valid = (node < NN);

#pragma unroll
    for (int ks = 0; ks < 4; ks++) {
        float4 f0 = {0,0,0,0}, f1 = {0,0,0,0};
        if (valid) {
            const float4* xr = (const float4*)(rowp + ks * 32);
            f0 = xr[0]; f1 = xr[1];
        }
        union { s16x8 v; unsigned u32[4]; } af;
        __hip_bfloat162 p0 = __float22bfloat162_rn({f0.x, f0.y});
        __hip_bfloat162 p1 = __float22bfloat162_rn({f0.z, f0.w});
        __hip_bfloat162 p2 = __float22bfloat162_rn({f1.x, f1.y});
        __hip_bfloat162 p3 = __float22bfloat162_rn({f1.z, f1.w});
        af.u32[0] = *(unsigned*)&p0;
        af.u32[1] = *(unsigned*)&p1;
        af.u32[2] = *(unsigned*)&p2;
        af.u32[3] = *(unsigned*)&p3;
        acc0 = __builtin_amdgcn_mfma_f32_16x16x32_bf16(af.v, wf[ks * 2 + 0], acc0, 0, 0, 0);
        acc1 = __builtin_amdgcn_mfma_f32_16x16x32_bf16(af.v, wf[ks * 2 + 1], acc1, 0, 0, 0);
    }

    int f = lane & 15;
#pragma unroll
    for (int r = 0; r < 4; r++) {
        int n2 = base + q * 4 + r;
        if (n2 < NN) {
            float dv = dinv[n2];
            hs[(size_t)n2 * HID + f]      = __float2bfloat16(dv * acc0[r]);
            hs[(size_t)n2 * HID + f + 16] = __float2bfloat16(dv * acc1[r]);
        }
    }
}

// ---------------- fused: per-bucket gather + LDS counting sort + register pull + epilogue ----
__global__ __launch_bounds__(512) void k_agg(const int* __restrict__ offsT,
                                             const uint2* __restrict__ raw,
                                             const bf16* __restrict__ hs,
                                             const float* __restrict__ dinv,
                                             const float* __restrict__ b1, const float* __restrict__ W2,
                                             const float* __restrict__ b2, float* __restrict__ out) {
    __shared__ uint2 se[SSPAN];               // 36.9 KB (sorted records); aliased by runid in phase A
    __shared__ int P[PBLK + 1];               //  3.1 KB
    __shared__ int basearr[PBLK];             //  3.1 KB  (= O0[r] - P[r])
    __shared__ int hist[BNODES];
    __shared__ int scanbuf[BNODES];
    __shared__ int cur[BNODES];
    __shared__ int wt8[8];

    unsigned short* runid = (unsigned short*)se;   // dead before se is written

    int t = threadIdx.x;
    int b = blockIdx.x;
    if (t < BNODES) hist[t] = 0;

    // run lengths for this bucket across 782 partition blocks (2 per thread)
    int e0 = 2 * t, e1 = 2 * t + 1;
    int l0 = 0, l1 = 0, o0v = 0, o1v = 0;
    if (e0 < PBLK) {
        o0v = offsT[(size_t)b * PBLK + e0];
        l0  = offsT[(size_t)(b + 1) * PBLK + e0] - o0v;
    }
    if (e1 < PBLK) {
        o1v = offsT[(size_t)b * PBLK + e1];
        l1  = offsT[(size_t)(b + 1) * PBLK + e1] - o1v;
    }
    int psum = l0 + l1;
    int lane = t & 63;
    int incl = psum;
#pragma unroll
    for (int off = 1; off < 64; off <<= 1) {
        int up = __shfl_up(incl, off, 64);
        if (lane >= off) incl += up;
    }
    int wid = t >> 6;
    if (lane == 63) wt8[wid] = incl;
    __syncthreads();
    int woff = 0;
    for (int wj = 0; wj < wid; wj++) woff += wt8[wj];
    int exc = woff + incl - psum;
    if (e0 < PBLK) { P[e0] = exc;      basearr[e0] = o0v - exc; }
    if (e1 < PBLK) { P[e1] = exc + l0; basearr[e1] = o1v - (exc + l0); }
    if (t == 0) {
        int s = 0;
#pragma unroll
        for (int j = 0; j < 8; j++) s += wt8[j];
        P[PBLK] = s;
    }
    __syncthreads();

    int total = min(P[PBLK], SSPAN);

    // build d -> run map in the se region (short serial LDS fills, ~5 per run)
    for (int r = t; r < PBLK; r += 512) {
        int p0 = P[r], p1 = min(P[r + 1], SSPAN);
        for (int i = p0; i < p1; i++) runid[i] = (unsigned short)r;
    }
    __syncthreads();

    // pass 1: coalesced gather into REGISTERS + node histogram (<=9 recs/thread)
    uint2 rr[9];
#pragma unroll
    for (int k = 0; k < 9; k++) {
        int d = t + k * 512;
        if (d < total) {
            int r = runid[d];
            uint2 rec = raw[(size_t)r * EPB + (basearr[r] + d)];
            rr[k] = rec;
            int dl = (rec.x >> 20) & 127;
            atomicAdd(&hist[dl], 1);
        }
    }
    __syncthreads();   // runid dead from here; se region reusable

    // inclusive scan of node hist (Hillis-Steele over 128)
    if (t < BNODES) scanbuf[t] = hist[t];
    __syncthreads();
    for (int off = 1; off < BNODES; off <<= 1) {
        int v = 0;
        if (t < BNODES && t >= off) v = scanbuf[t - off];
        __syncthreads();
        if (t < BNODES) scanbuf[t] += v;
        __syncthreads();
    }
    if (t < BNODES) cur[t] = scanbuf[t] - hist[t];   // exclusive start
    __syncthreads();

    // pass 2: scatter from registers into se at final sorted positions (src pre-masked)
#pragma unroll
    for (int k = 0; k < 9; k++) {
        int d = t + k * 512;
        if (d < total) {
            uint2 rec = rr[k];
            int dl = (rec.x >> 20) & 127;
            int pos = atomicAdd(&cur[dl], 1);   // LDS int atomic
            se[pos] = make_uint2(rec.x & 0xFFFFF, rec.y);
        }
    }
    __syncthreads();

    // ---- phase B: per-group pull, register accumulate, fused epilogue ----
    int gid = t >> 4;          // 0..31, 16 lanes each
    int l = t & 15;
    const __hip_bfloat162* hs2 = (const __hip_bfloat162*)hs;  // row stride 16
#pragma unroll
    for (int nn = 0; nn < 4; nn++) {
        int dl = gid * 4 + nn;
        int cnt = hist[dl];
        int rs = scanbuf[dl] - cnt;
        float a0 = 0.f, a1 = 0.f;
        for (int bse = 0; bse < cnt; bse += 8) {
            int rem = cnt - bse;
            uint2 q0 = se[rs + bse];
            uint2 q1 = se[rs + bse + (rem > 1 ? 1 : 0)];
            uint2 q2 = se[rs + bse + (rem > 2 ? 2 : 0)];
            uint2 q3 = se[rs + bse + (rem > 3 ? 3 : 0)];
            uint2 q4 = se[rs + bse + (rem > 4 ? 4 : 0)];
            uint2 q5 = se[rs + bse + (rem > 5 ? 5 : 0)];
            uint2 q6 = se[rs + bse + (rem > 6 ? 6 : 0)];
            uint2 q7 = se[rs + bse + (rem > 7 ? 7 : 0)];
            float w0 = __uint_as_float(q0.y);
            float w1 = rem > 1 ? __uint_as_float(q1.y) : 0.f;
            float w2 = rem > 2 ? __uint_as_float(q2.y) : 0.f;
            float w3 = rem > 3 ? __uint_as_float(q3.y) : 0.f;
            float w4 = rem > 4 ? __uint_as_float(q4.y) : 0.f;
            float w5 = rem > 5 ? __uint_as_float(q5.y) : 0.f;
            float w6 = rem > 6 ? __uint_as_float(q6.y) : 0.f;
            float w7 = rem > 7 ? __uint_as_float(q7.y) : 0.f;
            __hip_bfloat162 h0 = hs2[(size_t)q0.x * 16 + l];
            __hip_bfloat162 h1 = hs2[(size_t)q1.x * 16 + l];
            __hip_bfloat162 h2 = hs2[(size_t)q2.x * 16 + l];
            __hip_bfloat162 h3 = hs2[(size_t)q3.x * 16 + l];
            __hip_bfloat162 h4 = hs2[(size_t)q4.x * 16 + l];
            __hip_bfloat162 h5 = hs2[(size_t)q5.x * 16 + l];
            __hip_bfloat162 h6 = hs2[(size_t)q6.x * 16 + l];
            __hip_bfloat162 h7 = hs2[(size_t)q7.x * 16 + l];
            float2 f0 = __bfloat1622float2(h0); a0 += w0 * f0.x; a1 += w0 * f0.y;
            float2 f1 = __bfloat1622float2(h1); a0 += w1 * f1.x; a1 += w1 * f1.y;
            float2 f2 = __bfloat1622float2(h2); a0 += w2 * f2.x; a1 += w2 * f2.y;
            float2 f3 = __bfloat1622float2(h3); a0 += w3 * f3.x; a1 += w3 * f3.y;
            float2 f4 = __bfloat1622float2(h4); a0 += w4 * f4.x; a1 += w4 * f4.y;
            float2 f5 = __bfloat1622float2(h5); a0 += w5 * f5.x; a1 += w5 * f5.y;
            float2 f6 = __bfloat1622float2(h6); a0 += w6 * f6.x; a1 += w6 * f6.y;
            float2 f7 = __bfloat1622float2(h7); a0 += w7 * f7.x; a1 += w7 * f7.y;
        }
        int node = b * BNODES + dl;
        if (node < NN) {
            float dv = dinv[node];
            float2 fs = __bfloat1622float2(hs2[(size_t)node * 16 + l]);
            float v0 = dv * (a0 + fs.x) + b1[2 * l];
            float v1 = dv * (a1 + fs.y) + b1[2 * l + 1];
            v0 = fmaxf(v0, 0.f);
            v1 = fmaxf(v1, 0.f);
            float ps = v0 * W2[2 * l] + v1 * W2[2 * l + 1];
#pragma unroll
            for (int m2 = 8; m2 >= 1; m2 >>= 1) ps += __shfl_xor(ps, m2, 16);
            if (l == 0) out[node] = ps + b2[0];
        }
    }
}

// ---------------- launch ----------------
extern "C" void kernel_launch(void* const* d_in, const int* in_sizes, int n_in,
                              void* d_out, int out_size, void* d_ws, size_t ws_size,
                              hipStream_t stream) {
    const float* x  = (const float*)d_in[0];
    const int*   ei = (const int*)d_in[1];
    const float* ew = (const float*)d_in[2];
    const float* W1 = (const float*)d_in[3];
    const float* b1 = (const float*)d_in[4];
    const float* W2 = (const float*)d_in[5];
    const float* b2 = (const float*)d_in[6];
    float* out = (float*)d_out;

    char* ws = (char*)d_ws;
    // ws layout (bytes), total ~37.7 MB. raw stays live through k_agg (no overlap).
    uint2*          raw      = (uint2*)         (ws + 0);           // PBLK*EPB uint2 = 25,624,576
    int*            offs     = (int*)           (ws + 25624576);    // PBLK*NBP1 int = 2,449,224 -> pad 28,073,984
    int*            offsT    = (int*)           (ws + 28073984);    // NBP1*PBLK int -> pad 30,523,392
    bf16*           hs       = (bf16*)          (ws + 30523392);    // NN*HID bf16 = 6,400,000 -> 36,923,392
    float*          dinv     = (float*)         (ws + 36923392);    // NN floats -> 37,323,392
    unsigned short* wfrag    = (unsigned short*)(ws + 37323392);    // 8 KB -> 37,331,584

    k_w1frag<<<1, 64, 0, stream>>>(W1, wfrag);
    k_part<<<PBLK, 512, 0, stream>>>(ei, ew, offs, raw);
    k_trans<<<dim3((NBP1 + 31) / 32, (PBLK + 31) / 32), 256, 0, stream>>>(offs, offsT);
    k_deg<<<NB, 512, 0, stream>>>(offsT, raw, dinv);
    k_hs<<<(NN + 63) / 64, 256, 0, stream>>>(x, wfrag, dinv, hs);
    k_agg<<<NB, 512, 0, stream>>>(offsT, raw, hs, dinv, b1, W2, b2, out);
}

// Round 7
// 201.594 us; speedup vs baseline: 4.9081x; 1.0810x over previous
//
#include <hip/hip_runtime.h>
#include <hip/hip_bf16.h>
#include <hip/hip_fp16.h>

#define NN 100000
#define NE 3200000
#define IN_F 128
#define HID 32

#define BNODES 196      // nodes per bucket (dst / 196)
#define NB 511          // ceil(NN/BNODES) -> 2.0 blocks/CU on 256 CUs
#define NBP1 (NB + 1)
#define PBLK 768        // partition blocks -> 3.0 blocks/CU
#define EPB 4168        // ceil(NE/PBLK) edges per partition block
#define SSPAN 6912      // per-bucket span bound: mean 6272 + 8 sigma (79.2); = 13.5*512

typedef __hip_bfloat16 bf16;
typedef __attribute__((ext_vector_type(8))) short s16x8;   // 8 bf16 (4 VGPRs)
typedef __attribute__((ext_vector_type(4))) float f32x4;   // MFMA C/D

// ---------------- partition: LDS counting sort, ALL global writes dense ----------------
__global__ __launch_bounds__(512) void k_part(const int* __restrict__ ei,
                                              const float* __restrict__ ew,
                                              int* __restrict__ offs,
                                              uint2* __restrict__ raw) {
    __shared__ int hist[NB];
    __shared__ int start[NB];
    __shared__ int wtot8[8];
    __shared__ uint2 sp[EPB];             // 33.3 KB

    int t = threadIdx.x;
    int blk = blockIdx.x;
    if (t < NB) hist[t] = 0;
    __syncthreads();

    unsigned pk[9]; unsigned wb[9]; int bkt[9];
    int base_e = blk * EPB;
#pragma unroll
    for (int j = 0; j < 9; j++) {
        int idx = j * 512 + t;
        int e = base_e + idx;
        if (idx < EPB && e < NE) {
            int src = __builtin_nontemporal_load(ei + e);
            int dst = __builtin_nontemporal_load(ei + NE + e);
            float w = __builtin_nontemporal_load(ew + e);
            int bk = dst / BNODES;                 // magic-mul by compiler
            bkt[j] = bk;
            pk[j] = (unsigned)src | ((unsigned)(dst - bk * BNODES) << 20);
            wb[j] = __float_as_uint(w);
        } else bkt[j] = -1;
    }
#pragma unroll
    for (int j = 0; j < 9; j++)
        if (bkt[j] >= 0) atomicAdd(&hist[bkt[j]], 1);
    __syncthreads();

    // exclusive scan over 511 bins (1 per thread, shuffle-based)
    int h = (t < NB) ? hist[t] : 0;
    int lane = t & 63;
    int incl = h;
#pragma unroll
    for (int off = 1; off < 64; off <<= 1) {
        int up = __shfl_up(incl, off, 64);
        if (lane >= off) incl += up;
    }
    int wid = t >> 6;
    if (lane == 63) wtot8[wid] = incl;
    __syncthreads();
    int woff = 0;
    for (int wj = 0; wj < wid; wj++) woff += wtot8[wj];
    int exc = woff + incl - h;
    if (t < NB) start[t] = exc;
    __syncthreads();

    int total = start[NB - 1] + hist[NB - 1];
    int* orow = offs + (size_t)blk * NBP1;
    if (t < NB) orow[t] = start[t];
    if (t == 0) orow[NB] = total;
    __syncthreads();   // orow reads of start[] complete before cursor mutation

    // LDS counting scatter (start[] becomes cursor)
#pragma unroll
    for (int j = 0; j < 9; j++) {
        if (bkt[j] >= 0) {
            int pos = atomicAdd(&start[bkt[j]], 1);
            sp[pos] = make_uint2(pk[j], wb[j]);
        }
    }
    __syncthreads();

    // dense, coalesced copy to block-private region (written exactly once)
    uint2* r = raw + (size_t)blk * EPB;
    for (int i = t; i < total; i += 512) r[i] = sp[i];
}

// ---------------- offs transpose ([blk][bucket] -> [bucket][blk]) ----------------
__global__ __launch_bounds__(256) void k_trans(const int* __restrict__ in, int* __restrict__ out) {
    __shared__ int tile[32][33];
    int c0 = blockIdx.x * 32, r0 = blockIdx.y * 32;
    int tx = threadIdx.x & 31, ty = threadIdx.x >> 5;   // 32 x 8
    for (int i = ty; i < 32; i += 8) {
        int r = r0 + i, c = c0 + tx;
        if (r < PBLK && c < NBP1) tile[i][tx] = in[(size_t)r * NBP1 + c];
    }
    __syncthreads();
    for (int i = ty; i < 32; i += 8) {
        int c = c0 + i, r = r0 + tx;
        if (c < NBP1 && r < PBLK) out[(size_t)c * PBLK + r] = tile[tx][i];
    }
}

// ---------------- per-bucket weighted degree -> dinv (LDS atomics, dense writes) ----------
__global__ __launch_bounds__(512) void k_deg(const int* __restrict__ offsT,
                                             const uint2* __restrict__ raw,
                                             float* __restrict__ dinv) {
    __shared__ unsigned short runid[SSPAN];   // 13.8 KB
    __shared__ int P[PBLK + 1];               //  3.1 KB
    __shared__ int basearr[PBLK];             //  3.1 KB  (= O0[r] - P[r])
    __shared__ float wsum[BNODES];
    __shared__ int wt8[8];

    int t = threadIdx.x;
    int b = blockIdx.x;
    if (t < BNODES) wsum[t] = 0.f;

    int e0 = 2 * t, e1 = 2 * t + 1;
    int l0 = 0, l1 = 0, o0v = 0, o1v = 0;
    if (e0 < PBLK) {
        o0v = offsT[(size_t)b * PBLK + e0];
        l0  = offsT[(size_t)(b + 1) * PBLK + e0] - o0v;
    }
    if (e1 < PBLK) {
        o1v = offsT[(size_t)b * PBLK + e1];
        l1  = offsT[(size_t)(b + 1) * PBLK + e1] - o1v;
    }
    int psum = l0 + l1;
    int lane = t & 63;
    int incl = psum;
#pragma unroll
    for (int off = 1; off < 64; off <<= 1) {
        int up = __shfl_up(incl, off, 64);
        if (lane >= off) incl += up;
    }
    int wid = t >> 6;
    if (lane == 63) wt8[wid] = incl;
    __syncthreads();          // covers wsum init
    int woff = 0;
    for (int wj = 0; wj < wid; wj++) woff += wt8[wj];
    int exc = woff + incl - psum;
    if (e0 < PBLK) { P[e0] = exc;      basearr[e0] = o0v - exc; }
    if (e1 < PBLK) { P[e1] = exc + l0; basearr[e1] = o1v - (exc + l0); }
    if (t == 0) {
        int s = 0;
#pragma unroll
        for (int j = 0; j < 8; j++) s += wt8[j];
        P[PBLK] = s;
    }
    __syncthreads();

    int total = min(P[PBLK], SSPAN);

    for (int r = t; r < PBLK; r += 512) {
        int p0 = P[r], p1 = min(P[r + 1], SSPAN);
        for (int i = p0; i < p1; i++) runid[i] = (unsigned short)r;
    }
    __syncthreads();

#pragma unroll
    for (int k = 0; k < 14; k++) {
        int d = t + k * 512;
        if (d < total) {
            int r = runid[d];
            uint2 rec = raw[(size_t)r * EPB + (basearr[r] + d)];
            atomicAdd(&wsum[(rec.x >> 20) & 255], __uint_as_float(rec.y));
        }
    }
    __syncthreads();

    if (t < BNODES) {
        int node = b * BNODES + t;
        if (node < NN) dinv[node] = rsqrtf(wsum[t] + 1.0f);   // +1 = self-loop
    }
}

// ---------------- W1 -> bf16 MFMA B-fragments, lane-packed ----------------
__global__ void k_w1frag(const float* __restrict__ W1, unsigned short* __restrict__ wfrag) {
    int lane = threadIdx.x;   // 64 threads
    int q = lane >> 4;
    int n0 = lane & 15;
#pragma unroll
    for (int ks = 0; ks < 4; ks++) {
#pragma unroll
        for (int nt = 0; nt < 2; nt++) {
            int fi = ks * 2 + nt;
            int n = n0 + 16 * nt;
#pragma unroll
            for (int j = 0; j < 8; j++) {
                int k = ks * 32 + q * 8 + j;
                float v = W1[k * HID + n];
                __hip_bfloat16 bv = __float2bfloat16(v);
                wfrag[((size_t)fi * 64 + lane) * 8 + j] = *(unsigned short*)&bv;
            }
        }
    }
}

// ---------------- hs = dinv * (x @ W1) via MFMA, stored bf16 ----------------
__global__ __launch_bounds__(256) void k_hs(const float* __restrict__ x,
                                            const unsigned short* __restrict__ wfrag,
                                            const float* __restrict__ dinv,
                                            bf16* __restrict__ hs) {
    int t = threadIdx.x;
    int lane = t & 63;
    int wv = t >> 6;
    int base = blockIdx.x * 64 + wv * 16;
    int m = lane & 15;
    int q = lane >> 4;
    int node = base + m;

    s16x8 wf[8];
    const s16x8* wp = (const s16x8*)wfrag;
#pragma unroll
    for (int fi = 0; fi < 8; fi++) wf[fi] = wp[fi * 64 + lane];

    f32x4 acc0 = {0.f, 0.f, 0.f, 0.f};
    f32x4 acc1 = {0.f, 0.f, 0.f, 0.f};

    const float* rowp = x + (size_t)node * IN_F + q * 8;
    bool valid = (node < NN);

#pragma unroll
    for (int ks = 0; ks < 4; ks++) {
        float4 f0 = {0,0,0,0}, f1 = {0,0,0,0};
        if (valid) {
            const float4* xr = (const float4*)(rowp + ks * 32);
            f0 = xr[0]; f1 = xr[1];
        }
        union { s16x8 v; unsigned u32[4]; } af;
        __hip_bfloat162 p0 = __float22bfloat162_rn({f0.x, f0.y});
        __hip_bfloat162 p1 = __float22bfloat162_rn({f0.z, f0.w});
        __hip_bfloat162 p2 = __float22bfloat162_rn({f1.x, f1.y});
        __hip_bfloat162 p3 = __float22bfloat162_rn({f1.z, f1.w});
        af.u32[0] = *(unsigned*)&p0;
        af.u32[1] = *(unsigned*)&p1;
        af.u32[2] = *(unsigned*)&p2;
        af.u32[3] = *(unsigned*)&p3;
        acc0 = __builtin_amdgcn_mfma_f32_16x16x32_bf16(af.v, wf[ks * 2 + 0], acc0, 0, 0, 0);
        acc1 = __builtin_amdgcn_mfma_f32_16x16x32_bf16(af.v, wf[ks * 2 + 1], acc1, 0, 0, 0);
    }

    int f = lane & 15;
#pragma unroll
    for (int r = 0; r < 4; r++) {
        int n2 = base + q * 4 + r;
        if (n2 < NN) {
            float dv = dinv[n2];
            hs[(size_t)n2 * HID + f]      = __float2bfloat16(dv * acc0[r]);
            hs[(size_t)n2 * HID + f + 16] = __float2bfloat16(dv * acc1[r]);
        }
    }
}

// ---------------- fused: per-bucket gather + LDS counting sort + register pull + epilogue ----
__global__ __launch_bounds__(512) void k_agg(const int* __restrict__ offsT,
                                             const uint2* __restrict__ raw,
                                             const bf16* __restrict__ hs,
                                             const float* __restrict__ dinv,
                                             const float* __restrict__ b1, const float* __restrict__ W2,
                                             const float* __restrict__ b2, float* __restrict__ out) {
    __shared__ uint2 se[SSPAN];               // 55.3 KB (sorted records); aliased by runid in phase A
    __shared__ int P[PBLK + 1];               //  3.1 KB
    __shared__ int basearr[PBLK];             //  3.1 KB  (= O0[r] - P[r])
    __shared__ int hist[BNODES];
    __shared__ int scanbuf[BNODES];
    __shared__ int cur[BNODES];
    __shared__ int wt8[8];

    unsigned short* runid = (unsigned short*)se;   // dead before se is written

    int t = threadIdx.x;
    int b = blockIdx.x;
    if (t < BNODES) hist[t] = 0;

    // run lengths for this bucket across 768 partition blocks (2 per thread)
    int e0 = 2 * t, e1 = 2 * t + 1;
    int l0 = 0, l1 = 0, o0v = 0, o1v = 0;
    if (e0 < PBLK) {
        o0v = offsT[(size_t)b * PBLK + e0];
        l0  = offsT[(size_t)(b + 1) * PBLK + e0] - o0v;
    }
    if (e1 < PBLK) {
        o1v = offsT[(size_t)b * PBLK + e1];
        l1  = offsT[(size_t)(b + 1) * PBLK + e1] - o1v;
    }
    int psum = l0 + l1;
    int lane = t & 63;
    int incl = psum;
#pragma unroll
    for (int off = 1; off < 64; off <<= 1) {
        int up = __shfl_up(incl, off, 64);
        if (lane >= off) incl += up;
    }
    int wid = t >> 6;
    if (lane == 63) wt8[wid] = incl;
    __syncthreads();
    int woff = 0;
    for (int wj = 0; wj < wid; wj++) woff += wt8[wj];
    int exc = woff + incl - psum;
    if (e0 < PBLK) { P[e0] = exc;      basearr[e0] = o0v - exc; }
    if (e1 < PBLK) { P[e1] = exc + l0; basearr[e1] = o1v - (exc + l0); }
    if (t == 0) {
        int s = 0;
#pragma unroll
        for (int j = 0; j < 8; j++) s += wt8[j];
        P[PBLK] = s;
    }
    __syncthreads();

    int total = min(P[PBLK], SSPAN);

    // build d -> run map in the se region (short serial LDS fills, ~8 per run)
    for (int r = t; r < PBLK; r += 512) {
        int p0 = P[r], p1 = min(P[r + 1], SSPAN);
        for (int i = p0; i < p1; i++) runid[i] = (unsigned short)r;
    }
    __syncthreads();

    // pass 1: coalesced gather into REGISTERS + node histogram (<=14 recs/thread)
    uint2 rr[14];
#pragma unroll
    for (int k = 0; k < 14; k++) {
        int d = t + k * 512;
        if (d < total) {
            int r = runid[d];
            uint2 rec = raw[(size_t)r * EPB + (basearr[r] + d)];
            rr[k] = rec;
            int dl = (rec.x >> 20) & 255;
            atomicAdd(&hist[dl], 1);
        }
    }
    __syncthreads();   // runid dead from here; se region reusable

    // inclusive scan of node hist (Hillis-Steele over 196)
    if (t < BNODES) scanbuf[t] = hist[t];
    __syncthreads();
    for (int off = 1; off < BNODES; off <<= 1) {
        int v = 0;
        if (t < BNODES && t >= off) v = scanbuf[t - off];
        __syncthreads();
        if (t < BNODES) scanbuf[t] += v;
        __syncthreads();
    }
    if (t < BNODES) cur[t] = scanbuf[t] - hist[t];   // exclusive start
    __syncthreads();

    // pass 2: scatter from registers into se at final sorted positions
#pragma unroll
    for (int k = 0; k < 14; k++) {
        int d = t + k * 512;
        if (d < total) {
            uint2 rec = rr[k];
            int dl = (rec.x >> 20) & 255;
            int pos = atomicAdd(&cur[dl], 1);   // LDS int atomic
            se[pos] = make_uint2(rec.x & 0xFFFFF, rec.y);
        }
    }
    __syncthreads();

    // ---- phase B: per-group pull, register accumulate, fused epilogue ----
    int gid = t >> 4;          // 0..31, 16 lanes each
    int l = t & 15;
    const __hip_bfloat162* hs2 = (const __hip_bfloat162*)hs;  // row stride 16
    for (int dl = gid; dl < BNODES; dl += 32) {
        int cnt = hist[dl];
        int rs = scanbuf[dl] - cnt;
        float a0 = 0.f, a1 = 0.f;
        for (int bse = 0; bse < cnt; bse += 8) {
            int rem = cnt - bse;
            uint2 q0 = se[rs + bse];
            uint2 q1 = se[rs + bse + (rem > 1 ? 1 : 0)];
            uint2 q2 = se[rs + bse + (rem > 2 ? 2 : 0)];
            uint2 q3 = se[rs + bse + (rem > 3 ? 3 : 0)];
            uint2 q4 = se[rs + bse + (rem > 4 ? 4 : 0)];
            uint2 q5 = se[rs + bse + (rem > 5 ? 5 : 0)];
            uint2 q6 = se[rs + bse + (rem > 6 ? 6 : 0)];
            uint2 q7 = se[rs + bse + (rem > 7 ? 7 : 0)];
            float w0 = __uint_as_float(q0.y);
            float w1 = rem > 1 ? __uint_as_float(q1.y) : 0.f;
            float w2 = rem > 2 ? __uint_as_float(q2.y) : 0.f;
            float w3 = rem > 3 ? __uint_as_float(q3.y) : 0.f;
            float w4 = rem > 4 ? __uint_as_float(q4.y) : 0.f;
            float w5 = rem > 5 ? __uint_as_float(q5.y) : 0.f;
            float w6 = rem > 6 ? __uint_as_float(q6.y) : 0.f;
            float w7 = rem > 7 ? __uint_as_float(q7.y) : 0.f;
            __hip_bfloat162 h0 = hs2[(size_t)q0.x * 16 + l];
            __hip_bfloat162 h1 = hs2[(size_t)q1.x * 16 + l];
            __hip_bfloat162 h2 = hs2[(size_t)q2.x * 16 + l];
            __hip_bfloat162 h3 = hs2[(size_t)q3.x * 16 + l];
            __hip_bfloat162 h4 = hs2[(size_t)q4.x * 16 + l];
            __hip_bfloat162 h5 = hs2[(size_t)q5.x * 16 + l];
            __hip_bfloat162 h6 = hs2[(size_t)q6.x * 16 + l];
            __hip_bfloat162 h7 = hs2[(size_t)q7.x * 16 + l];
            float2 f0 = __bfloat1622float2(h0); a0 += w0 * f0.x; a1 += w0 * f0.y;
            float2 f1 = __bfloat1622float2(h1); a0 += w1 * f1.x; a1 += w1 * f1.y;
            float2 f2 = __bfloat1622float2(h2); a0 += w2 * f2.x; a1 += w2 * f2.y;
            float2 f3 = __bfloat1622float2(h3); a0 += w3 * f3.x; a1 += w3 * f3.y;
            float2 f4 = __bfloat1622float2(h4); a0 += w4 * f4.x; a1 += w4 * f4.y;
            float2 f5 = __bfloat1622float2(h5); a0 += w5 * f5.x; a1 += w5 * f5.y;
            float2 f6 = __bfloat1622float2(h6); a0 += w6 * f6.x; a1 += w6 * f6.y;
            float2 f7 = __bfloat1622float2(h7); a0 += w7 * f7.x; a1 += w7 * f7.y;
        }
        int node = b * BNODES + dl;
        if (node < NN) {
            float dv = dinv[node];
            float2 fs = __bfloat1622float2(hs2[(size_t)node * 16 + l]);
            float v0 = dv * (a0 + fs.x) + b1[2 * l];
            float v1 = dv * (a1 + fs.y) + b1[2 * l + 1];
            v0 = fmaxf(v0, 0.f);
            v1 = fmaxf(v1, 0.f);
            float ps = v0 * W2[2 * l] + v1 * W2[2 * l + 1];
#pragma unroll
            for (int m2 = 8; m2 >= 1; m2 >>= 1) ps += __shfl_xor(ps, m2, 16);
            if (l == 0) out[node] = ps + b2[0];
        }
    }
}

// ---------------- launch ----------------
extern "C" void kernel_launch(void* const* d_in, const int* in_sizes, int n_in,
                              void* d_out, int out_size, void* d_ws, size_t ws_size,
                              hipStream_t stream) {
    const float* x  = (const float*)d_in[0];
    const int*   ei = (const int*)d_in[1];
    const float* ew = (const float*)d_in[2];
    const float* W1 = (const float*)d_in[3];
    const float* b1 = (const float*)d_in[4];
    const float* W2 = (const float*)d_in[5];
    const float* b2 = (const float*)d_in[6];
    float* out = (float*)d_out;

    char* ws = (char*)d_ws;
    // ws layout (bytes), total ~35.6 MB.
    uint2*          raw      = (uint2*)         (ws + 0);           // PBLK*EPB uint2 = 25,608,192
    int*            offs     = (int*)           (ws + 25608192);    // PBLK*NBP1 int = 1,572,864 -> 27,181,056
    int*            offsT    = (int*)           (ws + 27181056);    // NBP1*PBLK int = 1,572,864 -> 28,753,920
    bf16*           hs       = (bf16*)          (ws + 28753920);    // NN*HID bf16 = 6,400,000 -> 35,153,920
    float*          dinv     = (float*)         (ws + 35153920);    // NN floats -> 35,553,920
    unsigned short* wfrag    = (unsigned short*)(ws + 35553920);    // 8 KB -> 35,562,112

    k_w1frag<<<1, 64, 0, stream>>>(W1, wfrag);
    k_part<<<PBLK, 512, 0, stream>>>(ei, ew, offs, raw);
    k_trans<<<dim3((NBP1 + 31) / 32, (PBLK + 31) / 32), 256, 0, stream>>>(offs, offsT);
    k_deg<<<NB, 512, 0, stream>>>(offsT, raw, dinv);
    k_hs<<<(NN + 63) / 64, 256, 0, stream>>>(x, wfrag, dinv, hs);
    k_agg<<<NB, 512, 0, stream>>>(offsT, raw, hs, dinv, b1, W2, b2, out);
}